// Round 2
// baseline (433.563 us; speedup 1.0000x reference)
//
#include <hip/hip_runtime.h>
#include <hip/hip_bf16.h>
#include <stdint.h>

typedef __attribute__((ext_vector_type(8))) short short8;
typedef __attribute__((ext_vector_type(4))) float floatx4;

#define B_ 16
#define C_ 512
#define S_ 4096
#define D_ 16

__device__ __forceinline__ unsigned short f2bf(float f) {
    union { float f; unsigned int i; } v;
    v.f = f;
    unsigned int u = v.i;
    return (unsigned short)((u + 0x7FFFu + ((u >> 16) & 1u)) >> 16);
}
// convert 8 fp32 -> short8 of bf16 bits (RNE)
__device__ __forceinline__ short8 cvt8(const float* p) {
    short8 r;
#pragma unroll
    for (int j = 0; j < 8; ++j) r[j] = (short)f2bf(p[j]);
    return r;
}

// ---------------------------------------------------------------------------
// Kernel 1: q,k projection.  qkp[ks][row][n] (fp32), row = b*512+c,
// n in [0,16) = q (dot with Wq), n in [16,32) = k (dot with Wk).
// One wave: 16-row x 32-col tile over a K-chunk of 1024. fp32 loads,
// inline cvt to bf16 fragments; both operands K-contiguous -> no LDS.
// ---------------------------------------------------------------------------
__global__ __launch_bounds__(256) void qk_kernel(
    const float* __restrict__ x,
    const float* __restrict__ Wq,
    const float* __restrict__ bq,
    const float* __restrict__ Wk,
    const float* __restrict__ bk,
    float* __restrict__ qkp)   // [4][8192][32]
{
    int lane = threadIdx.x & 63;
    int w    = threadIdx.x >> 6;
    int gw   = blockIdx.x * 4 + w;     // 0..2047
    int row_tile = gw >> 2;            // 0..511  (16 rows each)
    int ks       = gw & 3;             // K-split 0..3
    int m  = lane & 15;
    int q8 = lane >> 4;
    int k0 = ks * 1024;

    const float* ax = x  + (size_t)(row_tile * 16 + m) * S_ + k0 + q8 * 8;
    const float* aq = Wq + (size_t)m * S_ + k0 + q8 * 8;
    const float* ak = Wk + (size_t)m * S_ + k0 + q8 * 8;

    floatx4 accq = {0.f, 0.f, 0.f, 0.f};
    floatx4 acck = {0.f, 0.f, 0.f, 0.f};
#pragma unroll 4
    for (int it = 0; it < 32; ++it) {
        short8 a   = cvt8(ax + it * 32);
        short8 bq8 = cvt8(aq + it * 32);
        short8 bk8 = cvt8(ak + it * 32);
        accq = __builtin_amdgcn_mfma_f32_16x16x32_bf16(a, bq8, accq, 0, 0, 0);
        acck = __builtin_amdgcn_mfma_f32_16x16x32_bf16(a, bk8, acck, 0, 0, 0);
    }
    float biasq = (ks == 0) ? bq[m] : 0.f;
    float biask = (ks == 0) ? bk[m] : 0.f;
    float* outp = qkp + (size_t)ks * 8192 * 32;
#pragma unroll
    for (int r = 0; r < 4; ++r) {
        int row = row_tile * 16 + q8 * 4 + r;    // C/D: row=(lane>>4)*4+reg
        outp[(size_t)row * 32 + m]      = accq[r] + biasq;
        outp[(size_t)row * 32 + 16 + m] = acck[r] + biask;
    }
}

// ---------------------------------------------------------------------------
// Kernel 2: kq[b,i,o] = q[b,i] . k[b,o]; softmax over b (axis 0!);
// write A transposed: Abf[b][o][i] (bf16) so kernel 3's A-operand rows are
// K(=i)-contiguous.
// ---------------------------------------------------------------------------
__global__ __launch_bounds__(256) void softmax_kernel(
    const float* __restrict__ qkp,        // [4][8192][32]
    unsigned short* __restrict__ Abf)     // [16][512][512] = [b][o][i]
{
    __shared__ float lq[B_][D_][32];   // [b][d][i_local]
    __shared__ float lk[B_][D_][32];   // [b][d][o_local]
    int i0 = blockIdx.x * 32;
    int o0 = blockIdx.y * 32;
    int tid = threadIdx.x;

    for (int f = tid; f < 8192; f += 256) {
        int b  = f >> 9;
        int il = (f >> 4) & 31;
        int d  = f & 15;
        size_t rq = (size_t)(b * C_ + i0 + il) * 32 + d;
        size_t rk = (size_t)(b * C_ + o0 + il) * 32 + 16 + d;
        float sq = 0.f, sk = 0.f;
#pragma unroll
        for (int ks = 0; ks < 4; ++ks) {
            sq += qkp[(size_t)ks * 8192 * 32 + rq];
            sk += qkp[(size_t)ks * 8192 * 32 + rk];
        }
        lq[b][d][il] = sq;
        lk[b][d][il] = sk;
    }
    __syncthreads();

    int i     = tid & 31;
    int obase = tid >> 5;     // 0..7
#pragma unroll
    for (int j = 0; j < 4; ++j) {
        int ol = obase + 8 * j;
        float v[16];
#pragma unroll
        for (int b = 0; b < 16; ++b) {
            float s = 0.f;
#pragma unroll
            for (int d = 0; d < 16; ++d) s += lq[b][d][i] * lk[b][d][ol];
            v[b] = s;
        }
        float mx = v[0];
#pragma unroll
        for (int b = 1; b < 16; ++b) mx = fmaxf(mx, v[b]);
        float sum = 0.f;
#pragma unroll
        for (int b = 0; b < 16; ++b) { v[b] = __expf(v[b] - mx); sum += v[b]; }
        float inv = 1.0f / sum;
#pragma unroll
        for (int b = 0; b < 16; ++b) {
            Abf[(size_t)(b * C_ + o0 + ol) * C_ + i0 + i] = f2bf(v[b] * inv);
        }
    }
}

// ---------------------------------------------------------------------------
// Kernel 3: out[b][o][s] = sum_i Abf[b][o][i] * x[b][i][s]
// Batched GEMM M=512(o) N=4096(s) K=512(i).  128x128 tile, BK=32,
// 4 waves x 64x64.  x loaded fp32, converted to bf16 into transposed LDS.
// ---------------------------------------------------------------------------
#define LDP 40

__global__ __launch_bounds__(256) void av_kernel(
    const unsigned short* __restrict__ Abf,  // [16][512][512] bf16
    const float* __restrict__ x,             // [16][512][4096] fp32
    float* __restrict__ out)                 // [16][512][4096] fp32
{
    __shared__ unsigned short At[128][LDP];  // [o_local][i_local]
    __shared__ unsigned short Xt[128][LDP];  // [s_local][i_local]
    int b  = blockIdx.z;
    int o0 = blockIdx.y * 128;
    int s0 = blockIdx.x * 128;
    int tid  = threadIdx.x;
    int lane = tid & 63;
    int w    = tid >> 6;
    int wm = (w >> 1) * 64;
    int wn = (w & 1) * 64;
    int fm = lane & 15;
    int q8 = lane >> 4;

    floatx4 acc[4][4];
#pragma unroll
    for (int a = 0; a < 4; ++a)
#pragma unroll
        for (int c = 0; c < 4; ++c) acc[a][c] = (floatx4){0.f, 0.f, 0.f, 0.f};

    const unsigned short* Ab = Abf + (size_t)b * C_ * C_;
    const float* xb = x + (size_t)b * C_ * S_;

    int arow = tid >> 1;            // 0..127
    int ach  = (tid & 1) * 16;      // 0 / 16
    int xii  = tid >> 3;            // 0..31
    int xss  = (tid & 7) * 16;      // 0..112

    for (int kb = 0; kb < 16; ++kb) {
        int i0 = kb * 32;
        // stage A tile (bf16, row-major, no transpose)
        {
            const short8* src = (const short8*)(Ab + (size_t)(o0 + arow) * C_ + i0 + ach);
            short8 v0 = src[0];
            short8 v1 = src[1];
            *(short8*)(&At[arow][ach])     = v0;
            *(short8*)(&At[arow][ach + 8]) = v1;
        }
        // stage X tile transposed with fp32->bf16 cvt: Xt[s_local][i_local]
        {
            const float* src = xb + (size_t)(i0 + xii) * S_ + s0 + xss;
            float4 v0 = *(const float4*)(src);
            float4 v1 = *(const float4*)(src + 4);
            float4 v2 = *(const float4*)(src + 8);
            float4 v3 = *(const float4*)(src + 12);
            Xt[xss + 0][xii]  = f2bf(v0.x); Xt[xss + 1][xii]  = f2bf(v0.y);
            Xt[xss + 2][xii]  = f2bf(v0.z); Xt[xss + 3][xii]  = f2bf(v0.w);
            Xt[xss + 4][xii]  = f2bf(v1.x); Xt[xss + 5][xii]  = f2bf(v1.y);
            Xt[xss + 6][xii]  = f2bf(v1.z); Xt[xss + 7][xii]  = f2bf(v1.w);
            Xt[xss + 8][xii]  = f2bf(v2.x); Xt[xss + 9][xii]  = f2bf(v2.y);
            Xt[xss + 10][xii] = f2bf(v2.z); Xt[xss + 11][xii] = f2bf(v2.w);
            Xt[xss + 12][xii] = f2bf(v3.x); Xt[xss + 13][xii] = f2bf(v3.y);
            Xt[xss + 14][xii] = f2bf(v3.z); Xt[xss + 15][xii] = f2bf(v3.w);
        }
        __syncthreads();

        short8 af[4], bfr[4];
#pragma unroll
        for (int t = 0; t < 4; ++t)
            af[t] = *(const short8*)(&At[wm + t * 16 + fm][q8 * 8]);
#pragma unroll
        for (int t = 0; t < 4; ++t)
            bfr[t] = *(const short8*)(&Xt[wn + t * 16 + fm][q8 * 8]);
#pragma unroll
        for (int a = 0; a < 4; ++a)
#pragma unroll
            for (int c = 0; c < 4; ++c)
                acc[a][c] = __builtin_amdgcn_mfma_f32_16x16x32_bf16(af[a], bfr[c], acc[a][c], 0, 0, 0);
        __syncthreads();
    }

    float* ob = out + (size_t)b * C_ * S_;
#pragma unroll
    for (int a = 0; a < 4; ++a) {
        int orow = o0 + wm + a * 16 + q8 * 4;
#pragma unroll
        for (int c = 0; c < 4; ++c) {
            int sc = s0 + wn + c * 16 + fm;
#pragma unroll
            for (int r = 0; r < 4; ++r)
                ob[(size_t)(orow + r) * S_ + sc] = acc[a][c][r];
        }
    }
}

extern "C" void kernel_launch(void* const* d_in, const int* in_sizes, int n_in,
                              void* d_out, int out_size, void* d_ws, size_t ws_size,
                              hipStream_t stream) {
    const float* x  = (const float*)d_in[0];
    const float* Wq = (const float*)d_in[1];
    const float* bq = (const float*)d_in[2];
    const float* Wk = (const float*)d_in[3];
    const float* bk = (const float*)d_in[4];
    float* out = (float*)d_out;

    float* qkp = (float*)d_ws;                                   // 4 MB
    unsigned short* Abf =
        (unsigned short*)((char*)d_ws + (size_t)4 * 8192 * 32 * sizeof(float)); // 8 MB

    qk_kernel<<<512, 256, 0, stream>>>(x, Wq, bq, Wk, bk, qkp);
    softmax_kernel<<<dim3(16, 16), 256, 0, stream>>>(qkp, Abf);
    av_kernel<<<dim3(32, 4, 16), 256, 0, stream>>>(Abf, x, out);
}

// Round 4
// 342.764 us; speedup vs baseline: 1.2649x; 1.2649x over previous
//
#include <hip/hip_runtime.h>
#include <hip/hip_bf16.h>
#include <stdint.h>

typedef __attribute__((ext_vector_type(8))) short short8;
typedef __attribute__((ext_vector_type(4))) float floatx4;

#define B_ 16
#define C_ 512
#define S_ 4096
#define D_ 16

__device__ __forceinline__ unsigned short f2bf(float f) {
    union { float f; unsigned int i; } v;
    v.f = f;
    unsigned int u = v.i;
    return (unsigned short)((u + 0x7FFFu + ((u >> 16) & 1u)) >> 16);
}
__device__ __forceinline__ unsigned int pack2bf(float lo, float hi) {
    __hip_bfloat162 h = __float22bfloat162_rn(make_float2(lo, hi));
    union { __hip_bfloat162 h; unsigned int u; } v;
    v.h = h;
    return v.u;
}
// 8 fp32 (two float4) -> short8 bf16 via packed cvt
__device__ __forceinline__ short8 cvt8p(float4 a, float4 b) {
    union { unsigned int u[4]; short8 s; } r;
    r.u[0] = pack2bf(a.x, a.y);
    r.u[1] = pack2bf(a.z, a.w);
    r.u[2] = pack2bf(b.x, b.y);
    r.u[3] = pack2bf(b.z, b.w);
    return r.s;
}

// ---------------------------------------------------------------------------
// Kernel 1: q,k projection.  qkp[ks][row][n] fp32, row=b*512+c,
// n<16 = q, n>=16 = k.  One wave: 16 rows x 32 cols over K-chunk 1024.
// ---------------------------------------------------------------------------
__global__ __launch_bounds__(256) void qk_kernel(
    const float* __restrict__ x,
    const float* __restrict__ Wq,
    const float* __restrict__ bq,
    const float* __restrict__ Wk,
    const float* __restrict__ bk,
    float* __restrict__ qkp)   // [4][8192][32]
{
    int lane = threadIdx.x & 63;
    int w    = threadIdx.x >> 6;
    int gw   = blockIdx.x * 4 + w;
    int row_tile = gw >> 2;
    int ks       = gw & 3;
    int m  = lane & 15;
    int q8 = lane >> 4;
    int k0 = ks * 1024;

    const float* ax = x  + (size_t)(row_tile * 16 + m) * S_ + k0 + q8 * 8;
    const float* aq = Wq + (size_t)m * S_ + k0 + q8 * 8;
    const float* ak = Wk + (size_t)m * S_ + k0 + q8 * 8;

    floatx4 accq = {0.f, 0.f, 0.f, 0.f};
    floatx4 acck = {0.f, 0.f, 0.f, 0.f};
#pragma unroll 4
    for (int it = 0; it < 32; ++it) {
        float4 xa = *(const float4*)(ax + it * 32);
        float4 xb2 = *(const float4*)(ax + it * 32 + 4);
        float4 qa = *(const float4*)(aq + it * 32);
        float4 qb = *(const float4*)(aq + it * 32 + 4);
        float4 ka = *(const float4*)(ak + it * 32);
        float4 kb2 = *(const float4*)(ak + it * 32 + 4);
        short8 a   = cvt8p(xa, xb2);
        short8 bq8 = cvt8p(qa, qb);
        short8 bk8 = cvt8p(ka, kb2);
        accq = __builtin_amdgcn_mfma_f32_16x16x32_bf16(a, bq8, accq, 0, 0, 0);
        acck = __builtin_amdgcn_mfma_f32_16x16x32_bf16(a, bk8, acck, 0, 0, 0);
    }
    float biasq = (ks == 0) ? bq[m] : 0.f;
    float biask = (ks == 0) ? bk[m] : 0.f;
    float* outp = qkp + (size_t)ks * 8192 * 32;
#pragma unroll
    for (int r = 0; r < 4; ++r) {
        int row = row_tile * 16 + q8 * 4 + r;
        outp[(size_t)row * 32 + m]      = accq[r] + biasq;
        outp[(size_t)row * 32 + 16 + m] = acck[r] + biask;
    }
}

// ---------------------------------------------------------------------------
// Kernel 1b: reduce the 4 K-split partials.  qred[row][n] = sum_ks qkp.
// ---------------------------------------------------------------------------
__global__ __launch_bounds__(256) void reduce_kernel(
    const float* __restrict__ qkp, float* __restrict__ qred)
{
    int g = blockIdx.x * 256 + threadIdx.x;   // 65536 float4s
    const float4* p = (const float4*)qkp + g;
    float4 a = p[0], b = p[65536], c = p[131072], d = p[196608];
    float4 r;
    r.x = a.x + b.x + c.x + d.x;
    r.y = a.y + b.y + c.y + d.y;
    r.z = a.z + b.z + c.z + d.z;
    r.w = a.w + b.w + c.w + d.w;
    ((float4*)qred)[g] = r;
}

// ---------------------------------------------------------------------------
// Kernel 2: kq[b,i,o] = q[b,i].k[b,o]; softmax over b; write A transposed
// as bf16 Abf[b][o][i].  Block = 32i x 16o, 512 threads, grid (16,32).
// ---------------------------------------------------------------------------
__global__ __launch_bounds__(512) void softmax_kernel(
    const float* __restrict__ qred,       // [8192][32]
    unsigned short* __restrict__ Abf)     // [16][512][512] = [b][o][i]
{
    __shared__ float lq[B_][32][17];
    __shared__ float lk[B_][16][17];
    int i0 = blockIdx.x * 32;
    int o0 = blockIdx.y * 16;
    int tid = threadIdx.x;

    {
        int d = tid & 15, il = tid >> 4;   // il 0..31
#pragma unroll
        for (int b = 0; b < 16; ++b)
            lq[b][il][d] = qred[(size_t)(b * C_ + i0 + il) * 32 + d];
    }
    if (tid < 256) {
        int d = tid & 15, ol = tid >> 4;   // ol 0..15
#pragma unroll
        for (int b = 0; b < 16; ++b)
            lk[b][ol][d] = qred[(size_t)(b * C_ + o0 + ol) * 32 + 16 + d];
    }
    __syncthreads();

    int i = tid & 31;
    int o = tid >> 5;    // 0..15
    float v[16];
#pragma unroll
    for (int b = 0; b < 16; ++b) {
        float s = 0.f;
#pragma unroll
        for (int d = 0; d < 16; ++d) s += lq[b][i][d] * lk[b][o][d];
        v[b] = s;
    }
    float mx = v[0];
#pragma unroll
    for (int b = 1; b < 16; ++b) mx = fmaxf(mx, v[b]);
    float sum = 0.f;
#pragma unroll
    for (int b = 0; b < 16; ++b) { v[b] = __expf(v[b] - mx); sum += v[b]; }
    float inv = 1.0f / sum;
#pragma unroll
    for (int b = 0; b < 16; ++b)
        Abf[(size_t)(b * C_ + o0 + o) * C_ + i0 + i] = f2bf(v[b] * inv);
}

// ---------------------------------------------------------------------------
// Kernel 3: out[b][o][s] = sum_i Abf[b][o][i] * x[b][i][s]
// 128x128 tile, BK=32, 4 waves x 64x64.  LDS tiles as u32 with word-pitch 20
// (80B rows: 16B-aligned b128 access).  Each At row = 16 data words
// (32 bf16); each thread stages 8 words (two uint4).  Xt transpose:
// pair-packed u32 writes (2 bf16 from adjacent i rows).
// ---------------------------------------------------------------------------
#define WP 20

__global__ __launch_bounds__(256) void av_kernel(
    const unsigned short* __restrict__ Abf,  // [16][512][512] bf16
    const float* __restrict__ x,             // [16][512][4096] fp32
    float* __restrict__ out)                 // [16][512][4096] fp32
{
    __shared__ unsigned int At[128 * WP];  // row=o_local, 16 words (32 bf16 i)
    __shared__ unsigned int Xt[128 * WP];  // row=s_local, 16 words (i-pairs)
    int b  = blockIdx.z;
    int o0 = blockIdx.y * 128;
    int s0 = blockIdx.x * 128;
    int tid  = threadIdx.x;
    int lane = tid & 63;
    int w    = tid >> 6;
    int wm = (w >> 1) * 64;
    int wn = (w & 1) * 64;
    int fm = lane & 15;
    int q8 = lane >> 4;

    floatx4 acc[4][4];
#pragma unroll
    for (int a = 0; a < 4; ++a)
#pragma unroll
        for (int c = 0; c < 4; ++c) acc[a][c] = (floatx4){0.f, 0.f, 0.f, 0.f};

    const unsigned short* Ab = Abf + (size_t)b * C_ * C_;
    const float* xb = x + (size_t)b * C_ * S_;

    int arow  = tid >> 1;        // 0..127
    int ahalf = tid & 1;         // 0/1 (16 bf16 = 8 words each)
    int ip    = tid & 15;        // i-pair 0..15 -> i = 2*ip
    int sblk  = tid >> 4;        // 0..15 -> s = sblk*8

    for (int kb = 0; kb < 16; ++kb) {
        int i0 = kb * 32;
        // stage A tile: 32B per thread (two 16B loads -> two 16B LDS writes)
        {
            const uint4* src = (const uint4*)(Ab + (size_t)(o0 + arow) * C_ + i0 + ahalf * 16);
            uint4 v0 = src[0];
            uint4 v1 = src[1];
            *(uint4*)(&At[arow * WP + ahalf * 8])     = v0;
            *(uint4*)(&At[arow * WP + ahalf * 8 + 4]) = v1;
        }
        // stage X tile transposed, pair-packed: Xt[s][ip] = {x[2ip][s], x[2ip+1][s]}
        {
            const float* xr0 = xb + (size_t)(i0 + 2 * ip) * S_ + s0 + sblk * 8;
            const float* xr1 = xr0 + S_;
            float4 a0 = *(const float4*)(xr0);
            float4 a1 = *(const float4*)(xr0 + 4);
            float4 b0 = *(const float4*)(xr1);
            float4 b1 = *(const float4*)(xr1 + 4);
            unsigned int* dst = &Xt[(sblk * 8) * WP + ip];
            dst[0 * WP] = pack2bf(a0.x, b0.x);
            dst[1 * WP] = pack2bf(a0.y, b0.y);
            dst[2 * WP] = pack2bf(a0.z, b0.z);
            dst[3 * WP] = pack2bf(a0.w, b0.w);
            dst[4 * WP] = pack2bf(a1.x, b1.x);
            dst[5 * WP] = pack2bf(a1.y, b1.y);
            dst[6 * WP] = pack2bf(a1.z, b1.z);
            dst[7 * WP] = pack2bf(a1.w, b1.w);
        }
        __syncthreads();

        short8 af[4], bfr[4];
#pragma unroll
        for (int t = 0; t < 4; ++t)
            af[t] = *(const short8*)(&At[(wm + t * 16 + fm) * WP + q8 * 4]);
#pragma unroll
        for (int t = 0; t < 4; ++t)
            bfr[t] = *(const short8*)(&Xt[(wn + t * 16 + fm) * WP + q8 * 4]);
#pragma unroll
        for (int a = 0; a < 4; ++a)
#pragma unroll
            for (int c = 0; c < 4; ++c)
                acc[a][c] = __builtin_amdgcn_mfma_f32_16x16x32_bf16(af[a], bfr[c], acc[a][c], 0, 0, 0);
        __syncthreads();
    }

    float* ob = out + (size_t)b * C_ * S_;
#pragma unroll
    for (int a = 0; a < 4; ++a) {
        int orow = o0 + wm + a * 16 + q8 * 4;
#pragma unroll
        for (int c = 0; c < 4; ++c) {
            int sc = s0 + wn + c * 16 + fm;
#pragma unroll
            for (int r = 0; r < 4; ++r)
                ob[(size_t)(orow + r) * S_ + sc] = acc[a][c][r];
        }
    }
}

extern "C" void kernel_launch(void* const* d_in, const int* in_sizes, int n_in,
                              void* d_out, int out_size, void* d_ws, size_t ws_size,
                              hipStream_t stream) {
    const float* x  = (const float*)d_in[0];
    const float* Wq = (const float*)d_in[1];
    const float* bq = (const float*)d_in[2];
    const float* Wk = (const float*)d_in[3];
    const float* bk = (const float*)d_in[4];
    float* out = (float*)d_out;

    float* qkp = (float*)d_ws;                                      // 4 MB @ 0
    float* qred = (float*)((char*)d_ws + (size_t)4 * 1024 * 1024);  // 1 MB @ 4M
    unsigned short* Abf =
        (unsigned short*)((char*)d_ws + (size_t)5 * 1024 * 1024);   // 8 MB @ 5M

    qk_kernel<<<512, 256, 0, stream>>>(x, Wq, bq, Wk, bk, qkp);
    reduce_kernel<<<256, 256, 0, stream>>>(qkp, qred);
    softmax_kernel<<<dim3(16, 32), 512, 0, stream>>>(qred, Abf);
    av_kernel<<<dim3(32, 4, 16), 256, 0, stream>>>(Abf, x, out);
}